// Round 10
// baseline (788.307 us; speedup 1.0000x reference)
//
#include <hip/hip_runtime.h>
#include <stdint.h>

// ParallelFcWithAttention: B=16384, F=10, D=512, H=8, DH=64
// v9c = v9b resubmission (R9 was an infra failure, kernel never ran), with the
// dead duplicated PV computation cleaned up.
// Structure: phase-1 waves = 2 heads x 4 N-slices, all 80 rows/wave (no pad
// waste), BK=32, tri-buffered B, depth-2 prefetch, ONE barrier per interval.
// scp_e = sQK_e + 20480 (3840 B, in-buffer, disjoint — R8's OOB bug fixed).
// Shuffle-free softmax; phase 2 verbatim v4.

typedef __bf16 bf16;
typedef __bf16 bf16x8 __attribute__((ext_vector_type(8)));
typedef float f32x4 __attribute__((ext_vector_type(4)));

#define EPS 1e-5f

static constexpr size_t O_ELEMS   = (size_t)16384 * 10 * 512;   // 83,886,080
static constexpr size_t O_BYTES   = O_ELEMS * 2;                // 167,772,160
static constexpr size_t WQKV_BYTES = (size_t)8 * 192 * 512 * 2; // 1,572,864

__device__ __forceinline__ void async_copy16(void* lds, const void* g) {
  // wave-uniform LDS base; HW scatters lane i at base + i*16; global addr per-lane
  __builtin_amdgcn_global_load_lds(
      (const __attribute__((address_space(1))) uint32_t*)g,
      (__attribute__((address_space(3))) uint32_t*)lds, 16, 0, 0);
}

// ---------------- pack weights to bf16 ----------------
// wqkv layout: [h][0:64 = Wq rows h*64.., 64:128 = Wk, 128:192 = Wv][512]
__global__ __launch_bounds__(256) void pack_weights(
    const float* __restrict__ Wq, const float* __restrict__ Wk,
    const float* __restrict__ Wv, const float* __restrict__ Wo,
    bf16* __restrict__ wqkv, bf16* __restrict__ wob) {
  int idx = blockIdx.x * 256 + threadIdx.x;
#pragma unroll
  for (int u = 0; u < 4; ++u) {
    int i = idx + u * 262144;
    if (i < 786432) {
      int pr = i >> 9, k = i & 511;
      int h = pr / 192, w = pr - h * 192;
      int t = w >> 6, r = w & 63;
      const float* src = (t == 0) ? Wq : ((t == 1) ? Wk : Wv);
      wqkv[i] = (bf16)src[(h * 64 + r) * 512 + k];
    } else {
      int j = i - 786432;
      wob[j] = (bf16)Wo[j];
    }
  }
}

// ---------------- fused kernel ----------------
// 512 threads, 8 batch (80 rows) per block. 1 block/CU. LDS 155648 B.
// phase 1: sA @0 [8 slabs][80 rows][128B] XOR-swizzled                  81920
//          sBuf0 @81920, sBuf1 @106496, sBuf2 @131072 (24576 each):
//            tri-buffered B chunk [2 heads][96 lines][128B] paired-row.
//          epilogue overlay: sQK_e = sBuf_e [80][256] swz (20480) with
//            scp_e = sBuf_e + 20480 [8][10][12] f32 (3840; ends 24320 < 24576);
//            vbuf_e = sBuf2 + e*10240 [80][64] bf16.
// phase 2 overlay: Ab0@0 Ab1@5120 | Bb0@10240 Bb1@43008 (end 75776)
//          lnb @0 [80][520] bf16 | partial @83200 [80][4][2] | stats @85760
__global__ __launch_bounds__(512, 2) void kern_fused(
    const float* __restrict__ x, const float* __restrict__ Wf,
    const float* __restrict__ bfv, const bf16* __restrict__ wqkv,
    const float* __restrict__ bq, const float* __restrict__ bk,
    const float* __restrict__ bv, bf16* __restrict__ O,
    const bf16* __restrict__ wob, const float* __restrict__ bo,
    const float* __restrict__ gamma, const float* __restrict__ beta,
    float* __restrict__ out) {
  __shared__ __align__(16) char smem[155648];
  char* sA = smem;
  char* sBuf0 = smem + 81920;
  char* sBuf1 = smem + 106496;
  char* sBuf2 = smem + 131072;

  const int tid = threadIdx.x;
  const int wave = tid >> 6;
  const int lane = tid & 63;
  const int lm = lane & 15;
  const int lg = lane >> 4;
  const int whh = wave >> 2;               // which head of the pair (0/1)
  const int wnl = wave & 3;                // N-slice within head (48 cols)
  const int wm = whh, wn = wnl;            // phase-2 aliases (v4 roles)
  const int b0 = blockIdx.x * 8;
  const int x7 = lm & 7;
  // staging lane geometry (paired-row layout; R7-verified formulas):
  const int srow  = lane >> 2;                       // row within 16-row copy
  const int sgran = (lane & 3) ^ ((lane >> 3) & 3);  // pre-swizzled granule

  // stage k-chunk j_ (32 k = 64B/row) of head-pair g_ (heads 2g_,2g_+1):
  // 24 copies of 1KB (16 rows each), 3 per wave; dest wave-uniform.
#define STAGE1(buf_, g_, j_)                                                   \
  {                                                                            \
    _Pragma("unroll")                                                          \
    for (int jb = 0; jb < 3; ++jb) {                                           \
      int c = wave + 8 * jb;                                                   \
      int hh = c / 12;                                                         \
      int lr = c - hh * 12;                                                    \
      async_copy16((buf_) + hh * 12288 + lr * 1024,                            \
          (const char*)wqkv + (size_t)((g_) * 2 + hh) * 196608 +               \
          (size_t)(lr * 16 + srow) * 1024 + (size_t)(j_) * 64 + sgran * 16);   \
    }                                                                          \
  }

  // ---- prologue: stage (g=0, chunks 0,1) (hides under P compute) ----
  STAGE1(sBuf0, 0, 0);
  STAGE1(sBuf1, 0, 1);

  // ---- compute P = relu(x*Wf + bf) into sA (80 real rows) ----
#pragma unroll
  for (int it = 0; it < 10; ++it) {
    int c = tid + it * 512;                // 5120 chunks: c = s*640 + r*8 + kcp
    int s = c / 640, rem = c - s * 640;
    int r = rem >> 3, kcp = rem & 7;
    int kc = kcp ^ (r & 7);
    int k = s * 64 + kc * 8;
    int bl = r / 10, f = r - bl * 10;
    float xv = x[(b0 + bl) * 10 + f];
    const float* wf = Wf + f * 512 + k;
    const float* bp = bfv + f * 512 + k;
    bf16x8 pv;
#pragma unroll
    for (int j = 0; j < 8; ++j) pv[j] = (bf16)fmaxf(xv * wf[j] + bp[j], 0.f);
    *(bf16x8*)(sA + s * 10240 + r * 128 + kcp * 16) = pv;
  }
  __syncthreads();   // P visible; chunks 0,1 landed (full drain, once)

  // B-frag LDS offsets (chunk-invariant): head base + paired-row position
  int noff[3];
#pragma unroll
  for (int nt = 0; nt < 3; ++nt) {
    int n = wnl * 48 + nt * 16 + lm, line = n >> 1;
    noff[nt] = whh * 12288 + line * 128 + (n & 1) * 64 + ((lg ^ (line & 3)) << 4);
  }

  for (int g = 0; g < 4; ++g) {
    f32x4 acc[5][3];
#pragma unroll
    for (int i = 0; i < 5; ++i)
#pragma unroll
      for (int j = 0; j < 3; ++j) { f32x4 z = {0.f, 0.f, 0.f, 0.f}; acc[i][j] = z; }

#pragma unroll
    for (int j = 0; j < 16; ++j) {         // 16 k-chunks of 32; ONE barrier each
      if (j == 15) asm volatile("s_waitcnt vmcnt(0)" ::: "memory");
      else         asm volatile("s_waitcnt vmcnt(3)" ::: "memory");  // stage(j) done
      __builtin_amdgcn_sched_barrier(0);
      __builtin_amdgcn_s_barrier();        // ALL stage(j) done; all done reading buf[j-1]
      __builtin_amdgcn_sched_barrier(0);
      if (j <= 13) {                       // overwrite buf[(j+2)%3]=buf[(j-1)%3]: safe now
        char* bufN = ((j + 2) % 3 == 0) ? sBuf0 : (((j + 2) % 3 == 1) ? sBuf1 : sBuf2);
        STAGE1(bufN, g, j + 2);
      }
      const char* bufC = (j % 3 == 0) ? sBuf0 : ((j % 3 == 1) ? sBuf1 : sBuf2);
      const char* sAj = sA + (j >> 1) * 10240;
      const int ch = (((j & 1) * 4 + lg) ^ x7) << 4;
      bf16x8 af[5], bfr[3];
#pragma unroll
      for (int mt = 0; mt < 5; ++mt)
        af[mt] = *(const bf16x8*)(sAj + (mt * 16 + lm) * 128 + ch);
#pragma unroll
      for (int nt = 0; nt < 3; ++nt)
        bfr[nt] = *(const bf16x8*)(bufC + noff[nt]);
      __builtin_amdgcn_s_setprio(1);
#pragma unroll
      for (int mt = 0; mt < 5; ++mt)
#pragma unroll
        for (int nt = 0; nt < 3; ++nt)
          acc[mt][nt] = __builtin_amdgcn_mfma_f32_16x16x32_bf16(af[mt], bfr[nt], acc[mt][nt], 0, 0, 0);
      __builtin_amdgcn_s_setprio(0);
    }

    __syncthreads();   // all GEMM reads done; all 3 buffers free

    // ---- spill both heads under one barrier: wave's head = whh ----
    {
      char* sQKe = (whh == 0) ? sBuf0 : sBuf1;          // [80][256] swizzled
      bf16* vbufe = (bf16*)(sBuf2 + whh * 10240);       // [80][64]
      const int h = g * 2 + whh;
      float bias[3];
#pragma unroll
      for (int nt = 0; nt < 3; ++nt) {
        int col = wnl * 48 + nt * 16 + lm;
        bias[nt] = (col < 64) ? bq[h * 64 + col]
                 : (col < 128) ? bk[h * 64 + col - 64]
                 : bv[h * 64 + col - 128];
      }
#pragma unroll
      for (int mt = 0; mt < 5; ++mt) {
        int rowb = mt * 16 + lg * 4;                    // rows all < 80 (no pad!)
#pragma unroll
        for (int r = 0; r < 4; ++r) {
          int rw = rowb + r;
#pragma unroll
          for (int nt = 0; nt < 3; ++nt) {
            int col = wnl * 48 + nt * 16 + lm;
            float val = acc[mt][nt][r] + bias[nt];
            if (col < 128)
              *(bf16*)(sQKe + rw * 256 + (((col >> 3) ^ (rw & 7)) << 4) + (col & 7) * 2) = (bf16)val;
            else
              vbufe[rw * 64 + (col - 128)] = (bf16)val;
          }
        }
      }
    }
    __syncthreads();   // q,k,v of BOTH heads visible

    // ---- scores + shuffle-free softmax + PV for both heads; wave = batch ----
    {
      const int bb = wave;
      const int d = lane;
#pragma unroll
      for (int e = 0; e < 2; ++e) {
        const int h = g * 2 + e;
        char* sQKe = (e == 0) ? sBuf0 : sBuf1;
        float* scpe = (float*)(sQKe + 20480);           // [8][10][12] f32, in-buffer
        bf16* vbufe = (bf16*)(sBuf2 + e * 10240);
        f32x4 sv = {0.f, 0.f, 0.f, 0.f};
        const int rowa = bb * 10 + lm;     // lm>=10: garbage rows; only D[i<10][j<10] used
        const int x7r = rowa & 7;
#pragma unroll
        for (int kk = 0; kk < 2; ++kk) {
          bf16x8 qf = *(const bf16x8*)(sQKe + rowa * 256 + (((kk * 4 + lg) ^ x7r) << 4));
          bf16x8 kf = *(const bf16x8*)(sQKe + rowa * 256 + (((8 + kk * 4 + lg) ^ x7r) << 4));
          sv = __builtin_amdgcn_mfma_f32_16x16x32_bf16(qf, kf, sv, 0, 0, 0);
        }
        // store UNNORMALIZED exp (|score| small -> f32-safe; v6/v7/v8-verified)
#pragma unroll
        for (int r = 0; r < 4; ++r) {
          int i = lg * 4 + r;
          if (i < 10 && lm < 12)
            scpe[(bb * 10 + i) * 12 + lm] = (lm < 10) ? __expf(sv[r] * 0.125f) : 0.f;
        }
        // PV (lane <-> d); scp rows wave-local, vbuf covered by spill barrier
        float vv[10];
#pragma unroll
        for (int jv = 0; jv < 10; ++jv) vv[jv] = (float)vbufe[(bb * 10 + jv) * 64 + d];
        bf16* Obp = O + ((size_t)(b0 + bb) * 10) * 512 + h * 64 + d;
#pragma unroll
        for (int i = 0; i < 10; ++i) {
          const float* ar = scpe + (bb * 10 + i) * 12;
          f32x4 a0 = *(const f32x4*)ar;
          f32x4 a1 = *(const f32x4*)(ar + 4);
          f32x4 a2 = *(const f32x4*)(ar + 8);   // [8],[9] real; [10],[11] zero
          float ssum = a0[0] + a0[1] + a0[2] + a0[3] + a1[0] + a1[1] + a1[2] + a1[3] + a2[0] + a2[1];
          float o = a0[0] * vv[0] + a0[1] * vv[1] + a0[2] * vv[2] + a0[3] * vv[3]
                  + a1[0] * vv[4] + a1[1] * vv[5] + a1[2] * vv[6] + a1[3] * vv[7]
                  + a2[0] * vv[8] + a2[1] * vv[9];
          Obp[(size_t)i * 512] = (bf16)(o / ssum);   // 128B contiguous per i
        }
      }
    }
    __syncthreads();   // epilogue buffers dead before re-staging

    if (g < 3) {       // prologue of next pass: chunks 0,1 -> buf0,buf1
      STAGE1(sBuf0, g + 1, 0);
      STAGE1(sBuf1, g + 1, 1);
    }
  }

  // ================= Phase 2: O @ Wo^T + bo -> LN -> sum over F =================
  // v4 verbatim: BK=32, dbuf A+B, raw barriers + counted vmcnt, paired-row layout.
  {
    char* Ab0 = smem;
    char* Ab1 = smem + 5120;
    char* Bb0 = smem + 10240;
    char* Bb1 = smem + 43008;
    float* partial = (float*)(smem + 83200);  // [80][4][2]
    float* stats   = (float*)(smem + 85760);  // [80][2]
    const char* Ob = (const char*)(O + (size_t)blockIdx.x * 80 * 512);
    const char* Wb = (const char*)wob;

    f32x4 acc[3][8];
#pragma unroll
    for (int i = 0; i < 3; ++i)
#pragma unroll
      for (int j = 0; j < 8; ++j) { f32x4 z = {0.f, 0.f, 0.f, 0.f}; acc[i][j] = z; }

#define STAGE2(AbN, BbN, s_)                                                     \
    {                                                                            \
      size_t co = (size_t)(s_) * 64 + sgran * 16;                                \
      _Pragma("unroll")                                                          \
      for (int j = 0; j < 4; ++j) {                                              \
        int R0 = (wave * 4 + j) * 16;                                            \
        async_copy16((BbN) + R0 * 64, Wb + (size_t)(R0 + srow) * 1024 + co);     \
      }                                                                          \
      if (wave < 5) {                                                            \
        int R0 = wave * 16;                                                      \
        async_copy16((AbN) + R0 * 64, Ob + (size_t)(R0 + srow) * 1024 + co);     \
      }                                                                          \
    }

    STAGE2(Ab0, Bb0, 0);                   // prologue

    for (int s = 0; s < 16; ++s) {
      char* AbC = (s & 1) ? Ab1 : Ab0;
      char* BbC = (s & 1) ? Bb1 : Bb0;
      char* AbN = (s & 1) ? Ab0 : Ab1;
      char* BbN = (s & 1) ? Bb0 : Bb1;
      if (s != 15) {
        STAGE2(AbN, BbN, s + 1);
        if (wave < 5) asm volatile("s_waitcnt vmcnt(5)" ::: "memory");
        else          asm volatile("s_waitcnt vmcnt(4)" ::: "memory");
      } else {
        asm volatile("s_waitcnt vmcnt(0)" ::: "memory");
      }
      __builtin_amdgcn_sched_barrier(0);
      __builtin_amdgcn_s_barrier();        // slab s visible
      __builtin_amdgcn_sched_barrier(0);

      bf16x8 a2[3], b2[8];
#pragma unroll
      for (int mt = 0; mt < 3; ++mt)
        if (mt < 2 || wm == 0) {
          int m = wm * 48 + mt * 16 + lm;
          a2[mt] = *(const bf16x8*)(AbC + (m >> 1) * 128 + (m & 1) * 64 + (((lg ^ ((m >> 1) & 3))) << 4));
        }
#pragma unroll
      for (int nt = 0; nt < 8; ++nt) {
        int n = wn * 128 + nt * 16 + lm;
        b2[nt] = *(const bf16x8*)(BbC + (n >> 1) * 128 + (n & 1) * 64 + (((lg ^ ((n >> 1) & 3))) << 4));
      }
      __builtin_amdgcn_s_setprio(1);
#pragma unroll
      for (int mt = 0; mt < 3; ++mt)
        if (mt < 2 || wm == 0)
#pragma unroll
          for (int nt = 0; nt < 8; ++nt)
            acc[mt][nt] = __builtin_amdgcn_mfma_f32_16x16x32_bf16(a2[mt], b2[nt], acc[mt][nt], 0, 0, 0);
      __builtin_amdgcn_s_setprio(0);

      asm volatile("s_waitcnt lgkmcnt(0)" ::: "memory");
      __builtin_amdgcn_sched_barrier(0);
      __builtin_amdgcn_s_barrier();        // release slab s buffers
      __builtin_amdgcn_sched_barrier(0);
    }

    // + bias
#pragma unroll
    for (int nt = 0; nt < 8; ++nt) {
      float bb = bo[wn * 128 + nt * 16 + lm];
#pragma unroll
      for (int mt = 0; mt < 3; ++mt)
#pragma unroll
        for (int r = 0; r < 4; ++r) acc[mt][nt][r] += bb;
    }

    // per-row mean/var: lane-local over 8 nt, then xor-shuffle across 16-lane col group
#pragma unroll
    for (int mt = 0; mt < 3; ++mt)
#pragma unroll
      for (int r = 0; r < 4; ++r) {
        float s1 = 0.f, s2 = 0.f;
#pragma unroll
        for (int nt = 0; nt < 8; ++nt) { float v = acc[mt][nt][r]; s1 += v; s2 += v * v; }
#pragma unroll
        for (int off = 1; off < 16; off <<= 1) {
          s1 += __shfl_xor(s1, off);
          s2 += __shfl_xor(s2, off);
        }
        if (lm == 0) {
          int row = wm * 48 + mt * 16 + lg * 4 + r;
          if (row < 80) {
            partial[(row * 4 + wn) * 2]     = s1;
            partial[(row * 4 + wn) * 2 + 1] = s2;
          }
        }
      }
    __syncthreads();
    if (tid < 80) {
      float s1 = 0.f, s2 = 0.f;
#pragma unroll
      for (int w = 0; w < 4; ++w) {
        s1 += partial[(tid * 4 + w) * 2];
        s2 += partial[(tid * 4 + w) * 2 + 1];
      }
      float mu = s1 * (1.f / 512.f);
      float var = s2 * (1.f / 512.f) - mu * mu;
      stats[tid * 2]     = mu;
      stats[tid * 2 + 1] = rsqrtf(var + EPS);
    }
    __syncthreads();
    // normalized values -> LDS bf16 (GEMM buffers dead), stride 520
    bf16* lnb = (bf16*)smem;
#pragma unroll
    for (int mt = 0; mt < 3; ++mt)
#pragma unroll
      for (int r = 0; r < 4; ++r) {
        int row = wm * 48 + mt * 16 + lg * 4 + r;
        if (row < 80) {
          float mu = stats[row * 2], rr = stats[row * 2 + 1];
#pragma unroll
          for (int nt = 0; nt < 8; ++nt) {
            int col = wn * 128 + nt * 16 + lm;
            lnb[row * 520 + col] = (bf16)((acc[mt][nt][r] - mu) * rr);
          }
        }
      }
    __syncthreads();
    // out[b,n] = gamma[n]*sum_f lnv + 10*beta[n]
#pragma unroll
    for (int u = 0; u < 8; ++u) {
      int id = tid + u * 512;              // 4096 outputs: 8b x 512n
      int b = id >> 9, n = id & 511;
      float ssum = 0.f;
#pragma unroll
      for (int f = 0; f < 10; ++f) ssum += (float)lnb[(b * 10 + f) * 520 + n];
      out[((size_t)blockIdx.x * 8 + b) * 512 + n] = gamma[n] * ssum + 10.f * beta[n];
    }
  }
#undef STAGE1
#undef STAGE2
}

extern "C" void kernel_launch(void* const* d_in, const int* in_sizes, int n_in,
                              void* d_out, int out_size, void* d_ws, size_t ws_size,
                              hipStream_t stream) {
  const float* x     = (const float*)d_in[0];
  const float* Wf    = (const float*)d_in[1];
  const float* bfv   = (const float*)d_in[2];
  const float* Wq    = (const float*)d_in[3];
  const float* Wk    = (const float*)d_in[4];
  const float* Wv    = (const float*)d_in[5];
  const float* bq    = (const float*)d_in[6];
  const float* bk    = (const float*)d_in[7];
  const float* bv    = (const float*)d_in[8];
  const float* Wo    = (const float*)d_in[9];
  const float* bo    = (const float*)d_in[10];
  const float* gamma = (const float*)d_in[11];
  const float* beta  = (const float*)d_in[12];
  float* out = (float*)d_out;

  char* ws = (char*)d_ws;
  bf16* O    = (bf16*)ws;                              // 167,772,160 B
  bf16* wqkv = (bf16*)(ws + O_BYTES);                  // 1,572,864 B
  bf16* wob  = (bf16*)(ws + O_BYTES + WQKV_BYTES);     // 524,288 B

  pack_weights<<<1024, 256, 0, stream>>>(Wq, Wk, Wv, Wo, wqkv, wob);
  kern_fused<<<2048, 512, 0, stream>>>(x, Wf, bfv, wqkv, bq, bk, bv, O,
                                       wob, bo, gamma, beta, out);
}